// Round 1
// baseline (2299.536 us; speedup 1.0000x reference)
//
#include <hip/hip_runtime.h>
#include <math.h>

#define NROWS 8192
#define HDIM  512
#define NCAT  100
#define NREL  69
#define NPOUT 69

// C = act(A_cat @ W + bias); A_cat = [A0|A1|A2], each (NROWS,512) f32 row-major.
// W is (K,M) row-major, K = NSRC*512. Tile 128x128, BK=8, 8x8 per thread.
// GUARDM: M may be < 128 (head GEMM, M=69).
template<int NSRC, bool RELU, bool GUARDM>
__global__ __launch_bounds__(256)
void gemm_k(const float* __restrict__ A0, const float* __restrict__ A1,
            const float* __restrict__ A2, const float* __restrict__ W,
            const float* __restrict__ bias, float* __restrict__ Cout, int M)
{
    __shared__ float As[8][128];   // [k][row]
    __shared__ float Bs[8][128];   // [k][col]
    const int t  = threadIdx.x;
    const int tx = t & 15, ty = t >> 4;
    const int row0 = blockIdx.y * 128;
    const int col0 = blockIdx.x * 128;

    const int arow = t >> 1;          // 0..127
    const int akq  = (t & 1) * 4;     // 0 or 4
    const int brow = t >> 5;          // 0..7
    const int bm   = (t & 31) * 4;    // 0..124

    float acc[8][8];
#pragma unroll
    for (int i = 0; i < 8; ++i)
#pragma unroll
        for (int j = 0; j < 8; ++j) acc[i][j] = 0.f;

    const int KT = NSRC * 64;

    auto loadA = [&](int kt) -> float4 {
        int gk = kt * 8;
        const float* Ap;
        if (NSRC == 1)      Ap = A0;
        else if (NSRC == 2) Ap = (gk < 512) ? A0 : A1;
        else                Ap = (gk < 512) ? A0 : ((gk < 1024) ? A1 : A2);
        int kcol = (gk & 511) + akq;
        return *(const float4*)&Ap[(size_t)(row0 + arow) * 512 + kcol];
    };
    auto loadB = [&](int kt) -> float4 {
        int gk = kt * 8 + brow;
        if (GUARDM) {
            float4 v; int c = col0 + bm;
            v.x = (c + 0 < M) ? W[(size_t)gk * M + c + 0] : 0.f;
            v.y = (c + 1 < M) ? W[(size_t)gk * M + c + 1] : 0.f;
            v.z = (c + 2 < M) ? W[(size_t)gk * M + c + 2] : 0.f;
            v.w = (c + 3 < M) ? W[(size_t)gk * M + c + 3] : 0.f;
            return v;
        }
        return *(const float4*)&W[(size_t)gk * M + col0 + bm];
    };

    float4 apf = loadA(0);
    float4 bpf = loadB(0);

    for (int kt = 0; kt < KT; ++kt) {
        __syncthreads();
        As[akq + 0][arow] = apf.x;
        As[akq + 1][arow] = apf.y;
        As[akq + 2][arow] = apf.z;
        As[akq + 3][arow] = apf.w;
        *(float4*)&Bs[brow][bm] = bpf;
        __syncthreads();
        if (kt + 1 < KT) { apf = loadA(kt + 1); bpf = loadB(kt + 1); }
#pragma unroll
        for (int k = 0; k < 8; ++k) {
            float a[8], b[8];
            *(float4*)&a[0] = *(const float4*)&As[k][ty * 8 + 0];
            *(float4*)&a[4] = *(const float4*)&As[k][ty * 8 + 4];
            *(float4*)&b[0] = *(const float4*)&Bs[k][tx * 8 + 0];
            *(float4*)&b[4] = *(const float4*)&Bs[k][tx * 8 + 4];
#pragma unroll
            for (int i = 0; i < 8; ++i)
#pragma unroll
                for (int j = 0; j < 8; ++j)
                    acc[i][j] = fmaf(a[i], b[j], acc[i][j]);
        }
    }

#pragma unroll
    for (int i = 0; i < 8; ++i) {
        int row = row0 + ty * 8 + i;
        if (GUARDM) {
#pragma unroll
            for (int j = 0; j < 8; ++j) {
                int c = col0 + tx * 8 + j;
                if (c < M) {
                    float v = acc[i][j] + bias[c];
                    if (RELU) v = fmaxf(v, 0.f);
                    Cout[(size_t)row * M + c] = v;
                }
            }
        } else {
#pragma unroll
            for (int jq = 0; jq < 2; ++jq) {
                int c = col0 + tx * 8 + jq * 4;
                float4 v;
                v.x = acc[i][jq * 4 + 0] + bias[c + 0];
                v.y = acc[i][jq * 4 + 1] + bias[c + 1];
                v.z = acc[i][jq * 4 + 2] + bias[c + 2];
                v.w = acc[i][jq * 4 + 3] + bias[c + 3];
                if (RELU) {
                    v.x = fmaxf(v.x, 0.f); v.y = fmaxf(v.y, 0.f);
                    v.z = fmaxf(v.z, 0.f); v.w = fmaxf(v.w, 0.f);
                }
                *(float4*)&Cout[(size_t)row * M + c] = v;
            }
        }
    }
}

// One block per row n. Single pass over rel rows with online softmax:
// reads rel[n,r,:] exactly once; accumulates attended in registers (2 f32/lane).
__global__ __launch_bounds__(256)
void attn_k(const float* __restrict__ vf, const float* __restrict__ rel,
            const int* __restrict__ scats, const int* __restrict__ ocats,
            float* __restrict__ att)
{
    const int n = blockIdx.x;
    const int t = threadIdx.x;
    const int lane = t & 63, wid = t >> 6;
    __shared__ float red[8];
    __shared__ float bc[2];
    __shared__ float s_vn;

    const float2 v2 = *(const float2*)&vf[(size_t)n * HDIM + t * 2];

    float pn = v2.x * v2.x + v2.y * v2.y;
#pragma unroll
    for (int off = 32; off > 0; off >>= 1) pn += __shfl_xor(pn, off, 64);
    if (lane == 0) red[wid] = pn;
    __syncthreads();
    if (t == 0) s_vn = sqrtf(red[0] + red[1] + red[2] + red[3]);
    __syncthreads();

    const int sc = scats[n], oc = ocats[n];
    const size_t base0   = (((size_t)sc * NREL) * NCAT + oc) * HDIM;
    const size_t rstride = (size_t)NCAT * HDIM;

    float m = -INFINITY, l = 0.f;
    float ox = 0.f, oy = 0.f;

    float2 cur = *(const float2*)&rel[base0 + t * 2];
    for (int r = 0; r < NREL; ++r) {
        float2 nxt = cur;
        if (r + 1 < NREL)
            nxt = *(const float2*)&rel[base0 + (size_t)(r + 1) * rstride + t * 2];

        float d = v2.x * cur.x + v2.y * cur.y;
        float q = cur.x * cur.x + cur.y * cur.y;
#pragma unroll
        for (int off = 32; off > 0; off >>= 1) {
            d += __shfl_xor(d, off, 64);
            q += __shfl_xor(q, off, 64);
        }
        if (lane == 0) { red[wid] = d; red[4 + wid] = q; }
        __syncthreads();
        if (t == 0) {
            float dot = red[0] + red[1] + red[2] + red[3];
            float rn  = sqrtf(red[4] + red[5] + red[6] + red[7]);
            float cs  = dot / fmaxf(s_vn * rn, 1e-8f);
            float mn  = fmaxf(m, cs);
            float alpha = expf(m - mn);
            float p     = expf(cs - mn);
            l = l * alpha + p;
            m = mn;
            bc[0] = alpha; bc[1] = p;
        }
        __syncthreads();
        float alpha = bc[0], p = bc[1];
        ox = ox * alpha + p * cur.x;
        oy = oy * alpha + p * cur.y;
        cur = nxt;
    }
    __syncthreads();
    if (t == 0) bc[0] = 1.f / l;
    __syncthreads();
    const float linv = bc[0];
    float2 o2 = make_float2(ox * linv, oy * linv);
    *(float2*)&att[(size_t)n * HDIM + t * 2] = o2;
}

extern "C" void kernel_launch(void* const* d_in, const int* in_sizes, int n_in,
                              void* d_out, int out_size, void* d_ws, size_t ws_size,
                              hipStream_t stream)
{
    const float* sf  = (const float*)d_in[0];
    const float* pf  = (const float*)d_in[1];
    const float* of  = (const float*)d_in[2];
    const float* rel = (const float*)d_in[3];
    const float* w1  = (const float*)d_in[4];
    const float* b1  = (const float*)d_in[5];
    const float* w2  = (const float*)d_in[6];
    const float* b2  = (const float*)d_in[7];
    const float* rw1 = (const float*)d_in[8];
    const float* rb1 = (const float*)d_in[9];
    const float* rw2 = (const float*)d_in[10];
    const float* rb2 = (const float*)d_in[11];
    const int* scats = (const int*)d_in[12];
    const int* ocats = (const int*)d_in[13];
    float* out = (float*)d_out;

    // workspace: h(16MB) | vf(16MB) | att(16MB); h2 reuses h's slot (h dead after GEMM2)
    float* h   = (float*)d_ws;
    float* vfb = h   + (size_t)NROWS * HDIM;
    float* att = vfb + (size_t)NROWS * HDIM;
    float* h2  = h;

    dim3 blk(256);
    // h = relu([s|p|o] @ w1 + b1)
    gemm_k<3, true,  false><<<dim3(4, 64), blk, 0, stream>>>(sf, pf, of, w1, b1, h, 512);
    // vf = relu(h @ w2 + b2)
    gemm_k<1, true,  false><<<dim3(4, 64), blk, 0, stream>>>(h, nullptr, nullptr, w2, b2, vfb, 512);
    // attended = softmax(cos(vf, rel)) @ rel   (single-pass, online softmax)
    attn_k<<<dim3(NROWS), blk, 0, stream>>>(vfb, rel, scats, ocats, att);
    // h2 = relu([vf|att] @ rw1 + rb1)
    gemm_k<2, true,  false><<<dim3(4, 64), blk, 0, stream>>>(vfb, att, nullptr, rw1, rb1, h2, 512);
    // plogits = h2 @ rw2 + rb2  (M=69, guarded)
    gemm_k<1, false, true ><<<dim3(1, 64), blk, 0, stream>>>(h2, nullptr, nullptr, rw2, rb2, out, 69);
}